// Round 16
// baseline (397.714 us; speedup 1.0000x reference)
//
#include <hip/hip_runtime.h>
#include <hip/hip_bf16.h>
#include <stdint.h>

typedef __attribute__((ext_vector_type(8))) short short8;
typedef __attribute__((ext_vector_type(4))) float f32x4;
typedef __attribute__((ext_vector_type(16))) float f32x16;
typedef __attribute__((ext_vector_type(2))) unsigned int uint2v;

__device__ __forceinline__ unsigned short f2bf(float f) {
  union { float f; unsigned int u; } v; v.f = f;
  unsigned int r = v.u + 0x7FFFu + ((v.u >> 16) & 1u);
  return (unsigned short)(r >> 16);
}

__device__ __forceinline__ unsigned int cvtpk(float lo, float hi) {
  unsigned int r;
  asm("v_cvt_pk_bf16_f32 %0, %1, %2" : "=v"(r) : "v"(lo), "v"(hi));
  return r;
}

#define GLOAD16(gsrc, ldst)                                                                  \
  __builtin_amdgcn_global_load_lds((const __attribute__((address_space(1))) void*)(gsrc),    \
                                   (__attribute__((address_space(3))) void*)(ldst), 16, 0, 0)

#define BAR() __builtin_amdgcn_s_barrier()
#define LGKM0() do { asm volatile("s_waitcnt lgkmcnt(0)" ::: "memory"); \
                     __builtin_amdgcn_sched_barrier(0); } while (0)
#define VMCNT0() asm volatile("s_waitcnt vmcnt(0)" ::: "memory")
#define PRIO(x) __builtin_amdgcn_s_setprio(x)
#define MFMA16(d, a, b) d = __builtin_amdgcn_mfma_f32_16x16x32_bf16(a, b, d, 0, 0, 0)

// ---------------- cast x (fp32 -> bf16), 4 elems/thread ----------------
__global__ __launch_bounds__(256) void cast_bf16_kernel(const float* __restrict__ in,
                                                        unsigned short* __restrict__ out) {
  int i = blockIdx.x * 256 + threadIdx.x;
  float4 v = ((const float4*)in)[i];
  ushort4 o;
  o.x = f2bf(v.x); o.y = f2bf(v.y); o.z = f2bf(v.z); o.w = f2bf(v.w);
  ((ushort4*)out)[i] = o;
}

// ---------------- transpose + cast W: [K][N] fp32 -> [N][K] bf16 ----------------
__global__ __launch_bounds__(256) void transpose_cast_kernel(const float* __restrict__ W,
                                                             unsigned short* __restrict__ Wt,
                                                             int K, int N) {
  __shared__ float tile[32][33];
  int n0 = blockIdx.x * 32, k0 = blockIdx.y * 32;
  int tx = threadIdx.x, ty = threadIdx.y;
#pragma unroll
  for (int j = 0; j < 32; j += 8)
    tile[ty + j][tx] = W[(size_t)(k0 + ty + j) * N + n0 + tx];
  __syncthreads();
#pragma unroll
  for (int j = 0; j < 32; j += 8)
    Wt[(size_t)(n0 + ty + j) * K + k0 + tx] = f2bf(tile[tx][ty + j]);
}

// ---------------- 128x256 GEMM mainloop: single-buffered, 2 blocks/CU (occupancy overlap) ----------------
// 256 threads = 4 waves (2Mx2N), wave tile 64x128, acc[4][8] f32x4 (128 AGPR).
// LDS: A 16KB + B 32KB = 48KB single buffer (64KB alloc) -> 2 blocks/CU; cross-block
// overlap hides stage latency + barrier stalls (m114 mechanism) instead of intra-block pipelining.
__device__ __forceinline__ void stageA128(const unsigned short* __restrict__ gp, int K,
                                          int kt, char* lds, int tid) {
#pragma unroll
  for (int it = 0; it < 4; ++it) {
    int li = it * 256 + tid;  // 0..1023 chunks of 16B (128 rows x 8 chunks)
    int r = li >> 3, c = li & 7;
    GLOAD16(gp + (size_t)r * K + kt * 64 + (c ^ (r & 7)) * 8, lds + li * 16);
  }
}
__device__ __forceinline__ void stageB256(const unsigned short* __restrict__ gp, int K,
                                          int kt, char* lds, int tid) {
#pragma unroll
  for (int it = 0; it < 8; ++it) {
    int li = it * 256 + tid;  // 0..2047 chunks (256 rows x 8 chunks)
    int r = li >> 3, c = li & 7;
    GLOAD16(gp + (size_t)r * K + kt * 64 + (c ^ (r & 7)) * 8, lds + li * 16);
  }
}

__device__ __forceinline__ void gemm128x256_mainloop(const unsigned short* __restrict__ Ap,
                                                     const unsigned short* __restrict__ Bp,
                                                     int K, int tid, char* smem,
                                                     f32x4 acc[4][8]) {
  char* sa = smem;           // 16 KB
  char* sb = smem + 16384;   // 32 KB
  const int KT = K >> 6;     // 32

  int wid = tid >> 6, lane = tid & 63;
  int wr = wid >> 1, wc = wid & 1;
  int lg = lane >> 4, l15 = lane & 15;
  int swz7 = l15 & 7;

#define LDA(m, kc) \
  (*(const short8*)((const unsigned short*)sa + (size_t)((wr * 64 + (m) * 16 + l15) * 64 + ((((kc) * 4 + lg) ^ swz7) * 8))))
#define LDB(n, kc) \
  (*(const short8*)((const unsigned short*)sb + (size_t)((wc * 128 + (n) * 16 + l15) * 64 + ((((kc) * 4 + lg) ^ swz7) * 8))))

  stageA128(Ap, K, 0, sa, tid);
  stageB256(Bp, K, 0, sb, tid);
  VMCNT0();
  BAR();

  for (int t = 0; t < KT; ++t) {
    short8 aq[4][2], bq[4][2];
    // ---- half 1: reads aq(8) + bq n0-3(8); MFMA n0-3 ----
#pragma unroll
    for (int m = 0; m < 4; ++m) { aq[m][0] = LDA(m, 0); aq[m][1] = LDA(m, 1); }
#pragma unroll
    for (int n = 0; n < 4; ++n) { bq[n][0] = LDB(n, 0); bq[n][1] = LDB(n, 1); }
    LGKM0();
    PRIO(1);
#pragma unroll
    for (int kc = 0; kc < 2; ++kc)
#pragma unroll
      for (int m = 0; m < 4; ++m)
#pragma unroll
        for (int n = 0; n < 4; ++n)
          MFMA16(acc[m][n], aq[m][kc], bq[n][kc]);
    PRIO(0);
    // ---- half 2: reads bq n4-7(8); MFMA n4-7 ----
#pragma unroll
    for (int n = 0; n < 4; ++n) { bq[n][0] = LDB(n + 4, 0); bq[n][1] = LDB(n + 4, 1); }
    LGKM0();
    PRIO(1);
#pragma unroll
    for (int kc = 0; kc < 2; ++kc)
#pragma unroll
      for (int m = 0; m < 4; ++m)
#pragma unroll
        for (int n = 0; n < 4; ++n)
          MFMA16(acc[m][n + 4], aq[m][kc], bq[n][kc]);
    PRIO(0);
    BAR();  // all waves done reading tile t
    if (t + 1 < KT) {
      stageA128(Ap, K, t + 1, sa, tid);
      stageB256(Bp, K, t + 1, sb, tid);
      VMCNT0();  // staged tile complete (other resident block computes meanwhile)
    }
    BAR();
  }
#undef LDA
#undef LDB
}

// ---------------- QKV GEMM 128x256: chunked XCD map; q/k + v^T via LDS for coalesced stores ----------------
__global__ __launch_bounds__(256, 2) void gemm_qkv256_kernel(const unsigned short* __restrict__ A,
                                                             const unsigned short* __restrict__ Bt,
                                                             const float* __restrict__ bias,
                                                             unsigned short* __restrict__ qb,
                                                             unsigned short* __restrict__ kb,
                                                             unsigned short* __restrict__ vtb) {
  extern __shared__ char smem[];
  int wg = blockIdx.x;                 // 1536 blocks
  int xcd = wg & 7, idx = wg >> 3;     // 192 per XCD
  int bn = xcd * 3 + idx % 3;          // 3 bn (256-col units) per XCD -> B panels L2-resident
  int bm = idx / 3;                    // 0..63 (128-row units)
  int tid = threadIdx.x;

  f32x4 acc[4][8];
  f32x4 zero = {0.f, 0.f, 0.f, 0.f};
#pragma unroll
  for (int m = 0; m < 4; ++m)
#pragma unroll
    for (int n = 0; n < 8; ++n) acc[m][n] = zero;

  gemm128x256_mainloop(A + (size_t)bm * 128 * 2048, Bt + (size_t)bn * 256 * 2048, 2048, tid, smem, acc);

  const float QSCALE = (float)(0.08838834764831845 * 1.4426950408889634);  // D^-0.5 * log2(e)
  int wid = tid >> 6, lane = tid & 63;
  int wr = wid >> 1, wc = wid & 1, lg = lane >> 4, l15 = lane & 15;

  if (bn >= 16) {
    // ---- v-block: col-major LDS [dloc 0..255][t 0..127], write [bh][d][t] coalesced ----
    int h0v = (bn - 16) * 2;
#pragma unroll
    for (int n = 0; n < 8; ++n) {
      int cl = wc * 128 + n * 16 + l15;  // 0..255 (= dloc)
      float bv = bias[bn * 256 + cl];
#pragma unroll
      for (int m = 0; m < 4; ++m) {
        int rl = wr * 64 + m * 16 + lg * 4;  // 0..124
        unsigned int w0 = cvtpk(acc[m][n][0] + bv, acc[m][n][1] + bv);
        unsigned int w1 = cvtpk(acc[m][n][2] + bv, acc[m][n][3] + bv);
        uint2v pk = {w0, w1};
        *(uint2v*)(smem + cl * 256 + ((rl * 2) ^ ((cl & 7) << 4))) = pk;
      }
    }
    LGKM0();
    BAR();
    int b = (bm * 128) >> 11, t0 = (bm * 128) & 2047;
#pragma unroll
    for (int i = 0; i < 16; ++i) {
      int id = i * 256 + tid;          // 4096 chunks
      int dloc = id >> 4, c = id & 15; // dloc 0..255, 16B-chunk 0..15
      short8 v = *(const short8*)(smem + dloc * 256 + ((c * 16) ^ ((dloc & 7) << 4)));
      int bh_ = b * 16 + h0v + (dloc >> 7);
      int d = dloc & 127;
      *(short8*)(vtb + ((size_t)bh_ * 128 + d) * 2048 + t0 + c * 8) = v;
    }
  } else {
    // ---- q/k block: row-major LDS [rl 0..127][cl 0..255], coalesced [bh][t][d] stores ----
    bool isq = (bn < 8);
#pragma unroll
    for (int n = 0; n < 8; ++n) {
      int cl = wc * 128 + n * 16 + l15;
      float bv = bias[bn * 256 + cl];
#pragma unroll
      for (int m = 0; m < 4; ++m) {
#pragma unroll
        for (int g = 0; g < 4; ++g) {
          int rl = wr * 64 + m * 16 + lg * 4 + g;  // 0..127
          float r = acc[m][n][g] + bv;
          if (isq) r *= QSCALE;
          *(unsigned short*)(smem + rl * 512 + ((cl * 2) ^ ((rl & 15) << 4))) = f2bf(r);
        }
      }
    }
    LGKM0();
    BAR();
    unsigned short* dst = isq ? qb : kb;
    int h0 = (bn & 7) * 2;
#pragma unroll
    for (int i = 0; i < 16; ++i) {
      int id = i * 256 + tid;          // 4096 chunks
      int rl = id >> 5, c8 = id & 31;  // row 0..127, chunk 0..31
      short8 v = *(const short8*)(smem + rl * 512 + ((c8 * 16) ^ ((rl & 15) << 4)));
      int row = bm * 128 + rl;
      int b = row >> 11, t = row & 2047;
      int h = h0 + (c8 >> 4);
      int d0 = (c8 & 15) * 8;
      *(short8*)(dst + ((size_t)(b * 16 + h) * 2048 + t) * 128 + d0) = v;
    }
  }
}

// ---------------- Proj GEMM 128x256: fp32 output + bias ----------------
__global__ __launch_bounds__(256, 2) void gemm_proj256_kernel(const unsigned short* __restrict__ A,
                                                              const unsigned short* __restrict__ Bt,
                                                              const float* __restrict__ bias,
                                                              float* __restrict__ out) {
  extern __shared__ char smem[];
  int wg = blockIdx.x;            // 512 blocks
  int bm = wg >> 3, bn = wg & 7;  // one bn column per XCD; B panel L2-resident
  int tid = threadIdx.x;

  f32x4 acc[4][8];
  f32x4 zero = {0.f, 0.f, 0.f, 0.f};
#pragma unroll
  for (int m = 0; m < 4; ++m)
#pragma unroll
    for (int n = 0; n < 8; ++n) acc[m][n] = zero;

  gemm128x256_mainloop(A + (size_t)bm * 128 * 2048, Bt + (size_t)bn * 256 * 2048, 2048, tid, smem, acc);

  int wid = tid >> 6, lane = tid & 63;
  int wr = wid >> 1, wc = wid & 1, lg = lane >> 4, l15 = lane & 15;
#pragma unroll
  for (int n = 0; n < 8; ++n) {
    int col = bn * 256 + wc * 128 + n * 16 + l15;
    float bv = bias[col];
#pragma unroll
    for (int m = 0; m < 4; ++m) {
#pragma unroll
      for (int g = 0; g < 4; ++g) {
        int row = bm * 128 + wr * 64 + m * 16 + lg * 4 + g;
        out[(size_t)row * 2048 + col] = acc[m][n][g] + bv;
      }
    }
  }
}

// ---------------- Flash attention: QBLK=256 (8 waves x 32 rows), paired q-tiles, dbuf K/V ----------------
__global__ __launch_bounds__(512) void attn_kernel(const unsigned short* __restrict__ qb,
                                                   const unsigned short* __restrict__ kb,
                                                   const unsigned short* __restrict__ vtb,
                                                   unsigned short* __restrict__ ob) {
  extern __shared__ char asmem[];
  int bh = blockIdx.x;     // 0..63 (same-XCD sharers for K/V L2 locality)
  int pairi = blockIdx.y;  // 0..3
  int b = bh >> 4, h = bh & 15;
  int tid = threadIdx.x, wid = tid >> 6, lane = tid & 63;
  int l31 = lane & 31, hi = lane >> 5;

  const unsigned short* Q  = qb  + (size_t)bh * 2048 * 128;
  const unsigned short* K  = kb  + (size_t)bh * 2048 * 128;
  const unsigned short* Vt = vtb + (size_t)bh * 128 * 2048;

#pragma unroll 1
  for (int pass = 0; pass < 2; ++pass) {
    int qt = pass == 0 ? (7 - pairi) : pairi;   // 256-row q-tile
    int NT = 4 * qt + 4;
    int qbase = qt * 256 + wid * 32;
    int qrow = qbase + l31;

    short8 qf[8];
#pragma unroll
    for (int kc = 0; kc < 8; ++kc)
      qf[kc] = *(const short8*)(Q + (size_t)qrow * 128 + kc * 16 + hi * 8);

    f32x16 o0 = {}, o1 = {}, o2 = {}, o3 = {};  // O^T[d][q=l31]
    float m_run = -1e30f, l_run = 0.f;

    {
      char* kb_ = asmem;
#pragma unroll
      for (int it = 0; it < 2; ++it) {
        int li = it * 512 + tid;
        int r = li >> 4, c = li & 15;
        GLOAD16(K + (size_t)r * 128 + (c ^ (r & 7)) * 8, kb_ + li * 16);
      }
#pragma unroll
      for (int it = 0; it < 2; ++it) {
        int li = it * 512 + tid;
        int r = li >> 3, c = li & 7;
        GLOAD16(Vt + (size_t)r * 2048 + (c ^ (r & 7)) * 8, kb_ + 16384 + li * 16);
      }
    }
    VMCNT0();
    BAR();

#pragma unroll 1
    for (int kt = 0; kt < NT; ++kt) {
      char* cb = asmem + ((kt & 1) << 15);
      if (kt + 1 < NT) {
        char* nb = asmem + (((kt + 1) & 1) << 15);
        int kt1 = kt + 1;
#pragma unroll
        for (int it = 0; it < 2; ++it) {
          int li = it * 512 + tid;
          int r = li >> 4, c = li & 15;
          GLOAD16(K + (size_t)(kt1 * 64 + r) * 128 + (c ^ (r & 7)) * 8, nb + li * 16);
        }
#pragma unroll
        for (int it = 0; it < 2; ++it) {
          int li = it * 512 + tid;
          int r = li >> 3, c = li & 7;
          GLOAD16(Vt + (size_t)r * 2048 + kt1 * 64 + (c ^ (r & 7)) * 8, nb + 16384 + li * 16);
        }
      }

      bool active = (kt * 64 <= qbase + 31);  // wave-uniform
      if (active) {
        const char* k_l = cb;
        const char* v_l = cb + 16384;

        f32x16 s0v = {}, s1v = {};
        PRIO(1);
#pragma unroll
        for (int kc = 0; kc < 8; ++kc) {
          int cg = kc * 2 + hi;
          int sw = l31 & 7;
          short8 kf0 = *(const short8*)(k_l + l31 * 256 + ((cg ^ sw) * 16));
          s0v = __builtin_amdgcn_mfma_f32_32x32x16_bf16(kf0, qf[kc], s0v, 0, 0, 0);
          short8 kf1 = *(const short8*)(k_l + (32 + l31) * 256 + ((cg ^ sw) * 16));
          s1v = __builtin_amdgcn_mfma_f32_32x32x16_bf16(kf1, qf[kc], s1v, 0, 0, 0);
        }
        PRIO(0);

        if (kt * 64 + 63 > qbase) {
          int kvb = kt * 64 + 4 * hi;
#pragma unroll
          for (int r = 0; r < 16; ++r) {
            int kv = kvb + (r & 3) + 8 * (r >> 2);
            if (kv > qrow) s0v[r] = -1e30f;
            if (kv + 32 > qrow) s1v[r] = -1e30f;
          }
        }

        float tmax[16];
#pragma unroll
        for (int i = 0; i < 16; ++i) tmax[i] = fmaxf(s0v[i], s1v[i]);
#pragma unroll
        for (int st = 8; st >= 1; st >>= 1)
#pragma unroll
          for (int i = 0; i < st; ++i) tmax[i] = fmaxf(tmax[i], tmax[i + st]);
        float pmax = fmaxf(tmax[0], __shfl_xor(tmax[0], 32));

        if (!__all(pmax <= m_run + 8.0f)) {
          float mn = fmaxf(m_run, pmax);
          float alpha = exp2f(m_run - mn);
          m_run = mn; l_run *= alpha;
          o0 *= alpha; o1 *= alpha; o2 *= alpha; o3 *= alpha;
        }

#pragma unroll
        for (int i = 0; i < 16; ++i) {
          s0v[i] = exp2f(s0v[i] - m_run);
          s1v[i] = exp2f(s1v[i] - m_run);
        }
        float tsum[16];
#pragma unroll
        for (int i = 0; i < 16; ++i) tsum[i] = s0v[i] + s1v[i];
#pragma unroll
        for (int st = 8; st >= 1; st >>= 1)
#pragma unroll
          for (int i = 0; i < st; ++i) tsum[i] += tsum[i + st];
        float rsum = tsum[0] + __shfl_xor(tsum[0], 32);
        l_run += rsum;

#define BUILD_PA(sv, base, out)                                                \
        {                                                                      \
          unsigned int a_ = cvtpk(sv[base + 0], sv[base + 1]);                 \
          unsigned int c_ = cvtpk(sv[base + 2], sv[base + 3]);                 \
          unsigned int b_ = cvtpk(sv[base + 4], sv[base + 5]);                 \
          unsigned int d_ = cvtpk(sv[base + 6], sv[base + 7]);                 \
          uint2v r0_ = __builtin_amdgcn_permlane32_swap(a_, b_, false, false); \
          uint2v r1_ = __builtin_amdgcn_permlane32_swap(c_, d_, false, false); \
          union { unsigned int u[4]; short8 v; } uu_;                          \
          uu_.u[0] = r0_[0]; uu_.u[1] = r1_[0]; uu_.u[2] = r0_[1]; uu_.u[3] = r1_[1]; \
          out = uu_.v;                                                         \
        }
        short8 pa0, pa1, pa2, pa3;
        BUILD_PA(s0v, 0, pa0);
        BUILD_PA(s0v, 8, pa1);
        BUILD_PA(s1v, 0, pa2);
        BUILD_PA(s1v, 8, pa3);
#undef BUILD_PA

        PRIO(1);
#define PV_STEP(ovar, dt)                                                          \
        {                                                                          \
          int rv_ = dt * 32 + l31;                                                 \
          const char* vb_ = v_l + rv_ * 128;                                       \
          int sw_ = rv_ & 7;                                                       \
          short8 v0_ = *(const short8*)(vb_ + (((0 + hi) ^ sw_) * 16));            \
          ovar = __builtin_amdgcn_mfma_f32_32x32x16_bf16(v0_, pa0, ovar, 0, 0, 0); \
          short8 v1_ = *(const short8*)(vb_ + (((2 + hi) ^ sw_) * 16));            \
          ovar = __builtin_amdgcn_mfma_f32_32x32x16_bf16(v1_, pa1, ovar, 0, 0, 0); \
          short8 v2_ = *(const short8*)(vb_ + (((4 + hi) ^ sw_) * 16));            \
          ovar = __builtin_amdgcn_mfma_f32_32x32x16_bf16(v2_, pa2, ovar, 0, 0, 0); \
          short8 v3_ = *(const short8*)(vb_ + (((6 + hi) ^ sw_) * 16));            \
          ovar = __builtin_amdgcn_mfma_f32_32x32x16_bf16(v3_, pa3, ovar, 0, 0, 0); \
        }
        PV_STEP(o0, 0)
        PV_STEP(o1, 1)
        PV_STEP(o2, 2)
        PV_STEP(o3, 3)
#undef PV_STEP
        PRIO(0);
      }

      VMCNT0();
      BAR();
    }

    float inv = 1.0f / l_run;
    size_t orow = (size_t)(b * 2048 + qt * 256 + wid * 32 + l31);
    unsigned short* ob_p = ob + orow * 2048 + h * 128;
#define STORE_DT(ovar, dt)                                                         \
    {                                                                              \
      _Pragma("unroll")                                                            \
      for (int rq = 0; rq < 4; ++rq) {                                             \
        unsigned int w0 = cvtpk(ovar[rq * 4 + 0] * inv, ovar[rq * 4 + 1] * inv);   \
        unsigned int w1 = cvtpk(ovar[rq * 4 + 2] * inv, ovar[rq * 4 + 3] * inv);   \
        uint2v st = {w0, w1};                                                      \
        *(uint2v*)(ob_p + dt * 32 + rq * 8 + 4 * hi) = st;                         \
      }                                                                            \
    }
    STORE_DT(o0, 0)
    STORE_DT(o1, 1)
    STORE_DT(o2, 2)
    STORE_DT(o3, 3)
#undef STORE_DT
  }
}

// ---------------- launch ----------------
extern "C" void kernel_launch(void* const* d_in, const int* in_sizes, int n_in,
                              void* d_out, int out_size, void* d_ws, size_t ws_size,
                              hipStream_t stream) {
  const float* x     = (const float*)d_in[0];
  const float* Wqkv  = (const float*)d_in[1];
  const float* bqkv  = (const float*)d_in[2];
  const float* Wproj = (const float*)d_in[3];
  const float* bproj = (const float*)d_in[4];
  float* out = (float*)d_out;

  char* ws = (char*)d_ws;
  unsigned short* x_bf   = (unsigned short*)ws;                         // 32MB, reused as attn_out
  unsigned short* wqkvt  = (unsigned short*)(ws + 33554432);            // 24MB
  unsigned short* wprojt = (unsigned short*)(ws + 33554432 + 25165824); // 8MB
  unsigned short* qb     = (unsigned short*)(ws + 67108864);            // 32MB (pre-scaled)
  unsigned short* kb     = (unsigned short*)(ws + 100663296);           // 32MB
  unsigned short* vtb    = (unsigned short*)(ws + 134217728);           // 32MB [bh][d][t]

  (void)hipFuncSetAttribute((const void*)gemm_qkv256_kernel,
                            hipFuncAttributeMaxDynamicSharedMemorySize, 65536);
  (void)hipFuncSetAttribute((const void*)gemm_proj256_kernel,
                            hipFuncAttributeMaxDynamicSharedMemorySize, 65536);
  (void)hipFuncSetAttribute((const void*)attn_kernel,
                            hipFuncAttributeMaxDynamicSharedMemorySize, 65536);

  cast_bf16_kernel<<<16384, 256, 0, stream>>>(x, x_bf);
  transpose_cast_kernel<<<dim3(192, 64), dim3(32, 8), 0, stream>>>(Wqkv, wqkvt, 2048, 6144);
  transpose_cast_kernel<<<dim3(64, 64), dim3(32, 8), 0, stream>>>(Wproj, wprojt, 2048, 2048);
  gemm_qkv256_kernel<<<1536, 256, 65536, stream>>>(x_bf, wqkvt, bqkv, qb, kb, vtb);
  attn_kernel<<<dim3(64, 4), 512, 65536, stream>>>(qb, kb, vtb, x_bf /* attn_out */);
  gemm_proj256_kernel<<<512, 256, 65536, stream>>>(x_bf, wprojt, bproj, out);
}

// Round 17
// 392.514 us; speedup vs baseline: 1.0132x; 1.0132x over previous
//
#include <hip/hip_runtime.h>
#include <hip/hip_bf16.h>
#include <stdint.h>

typedef __attribute__((ext_vector_type(8))) short short8;
typedef __attribute__((ext_vector_type(4))) float f32x4;
typedef __attribute__((ext_vector_type(16))) float f32x16;
typedef __attribute__((ext_vector_type(2))) unsigned int uint2v;

__device__ __forceinline__ unsigned short f2bf(float f) {
  union { float f; unsigned int u; } v; v.f = f;
  unsigned int r = v.u + 0x7FFFu + ((v.u >> 16) & 1u);
  return (unsigned short)(r >> 16);
}

__device__ __forceinline__ unsigned int cvtpk(float lo, float hi) {
  unsigned int r;
  asm("v_cvt_pk_bf16_f32 %0, %1, %2" : "=v"(r) : "v"(lo), "v"(hi));
  return r;
}

#define GLOAD16(gsrc, ldst)                                                                  \
  __builtin_amdgcn_global_load_lds((const __attribute__((address_space(1))) void*)(gsrc),    \
                                   (__attribute__((address_space(3))) void*)(ldst), 16, 0, 0)

#define BAR() __builtin_amdgcn_s_barrier()
#define LGKMC(n) do { asm volatile("s_waitcnt lgkmcnt(" #n ")" ::: "memory"); \
                      __builtin_amdgcn_sched_barrier(0); } while (0)
#define LGKM0() LGKMC(0)
#define VMCNT0() asm volatile("s_waitcnt vmcnt(0)" ::: "memory")
#define VMCNT8() do { asm volatile("s_waitcnt vmcnt(8)" ::: "memory"); \
                      __builtin_amdgcn_sched_barrier(0); } while (0)
#define PRIO(x) __builtin_amdgcn_s_setprio(x)
#define MFMA16(d, a, b) d = __builtin_amdgcn_mfma_f32_16x16x32_bf16(a, b, d, 0, 0, 0)

// ---------------- cast x (fp32 -> bf16), 4 elems/thread ----------------
__global__ __launch_bounds__(256) void cast_bf16_kernel(const float* __restrict__ in,
                                                        unsigned short* __restrict__ out) {
  int i = blockIdx.x * 256 + threadIdx.x;
  float4 v = ((const float4*)in)[i];
  ushort4 o;
  o.x = f2bf(v.x); o.y = f2bf(v.y); o.z = f2bf(v.z); o.w = f2bf(v.w);
  ((ushort4*)out)[i] = o;
}

// ---------------- transpose + cast W: [K][N] fp32 -> [N][K] bf16 ----------------
__global__ __launch_bounds__(256) void transpose_cast_kernel(const float* __restrict__ W,
                                                             unsigned short* __restrict__ Wt,
                                                             int K, int N) {
  __shared__ float tile[32][33];
  int n0 = blockIdx.x * 32, k0 = blockIdx.y * 32;
  int tx = threadIdx.x, ty = threadIdx.y;
#pragma unroll
  for (int j = 0; j < 32; j += 8)
    tile[ty + j][tx] = W[(size_t)(k0 + ty + j) * N + n0 + tx];
  __syncthreads();
#pragma unroll
  for (int j = 0; j < 32; j += 8)
    Wt[(size_t)(n0 + ty + j) * K + k0 + tx] = f2bf(tile[tx][ty + j]);
}

// ================= Mainloop variant A: 128x256, 256 thr, single-buffer, 2 blocks/CU =================
// (best measured for the QKV shape: MfmaUtil 49%, qkv 187 us)
__device__ __forceinline__ void stageA128(const unsigned short* __restrict__ gp, int K,
                                          int kt, char* lds, int tid) {
#pragma unroll
  for (int it = 0; it < 4; ++it) {
    int li = it * 256 + tid;  // 0..1023 chunks of 16B (128 rows x 8 chunks)
    int r = li >> 3, c = li & 7;
    GLOAD16(gp + (size_t)r * K + kt * 64 + (c ^ (r & 7)) * 8, lds + li * 16);
  }
}
__device__ __forceinline__ void stageB256(const unsigned short* __restrict__ gp, int K,
                                          int kt, char* lds, int tid) {
#pragma unroll
  for (int it = 0; it < 8; ++it) {
    int li = it * 256 + tid;  // 0..2047 chunks (256 rows x 8 chunks)
    int r = li >> 3, c = li & 7;
    GLOAD16(gp + (size_t)r * K + kt * 64 + (c ^ (r & 7)) * 8, lds + li * 16);
  }
}

__device__ __forceinline__ void gemm128x256_mainloop(const unsigned short* __restrict__ Ap,
                                                     const unsigned short* __restrict__ Bp,
                                                     int K, int tid, char* smem,
                                                     f32x4 acc[4][8]) {
  char* sa = smem;           // 16 KB
  char* sb = smem + 16384;   // 32 KB
  const int KT = K >> 6;     // 32

  int wid = tid >> 6, lane = tid & 63;
  int wr = wid >> 1, wc = wid & 1;
  int lg = lane >> 4, l15 = lane & 15;
  int swz7 = l15 & 7;

#define LDA(m, kc) \
  (*(const short8*)((const unsigned short*)sa + (size_t)((wr * 64 + (m) * 16 + l15) * 64 + ((((kc) * 4 + lg) ^ swz7) * 8))))
#define LDB(n, kc) \
  (*(const short8*)((const unsigned short*)sb + (size_t)((wc * 128 + (n) * 16 + l15) * 64 + ((((kc) * 4 + lg) ^ swz7) * 8))))

  stageA128(Ap, K, 0, sa, tid);
  stageB256(Bp, K, 0, sb, tid);
  VMCNT0();
  BAR();

  for (int t = 0; t < KT; ++t) {
    short8 aq[4][2], bq[4][2];
#pragma unroll
    for (int m = 0; m < 4; ++m) { aq[m][0] = LDA(m, 0); aq[m][1] = LDA(m, 1); }
#pragma unroll
    for (int n = 0; n < 4; ++n) { bq[n][0] = LDB(n, 0); bq[n][1] = LDB(n, 1); }
    LGKM0();
    PRIO(1);
#pragma unroll
    for (int kc = 0; kc < 2; ++kc)
#pragma unroll
      for (int m = 0; m < 4; ++m)
#pragma unroll
        for (int n = 0; n < 4; ++n)
          MFMA16(acc[m][n], aq[m][kc], bq[n][kc]);
    PRIO(0);
#pragma unroll
    for (int n = 0; n < 4; ++n) { bq[n][0] = LDB(n + 4, 0); bq[n][1] = LDB(n + 4, 1); }
    LGKM0();
    PRIO(1);
#pragma unroll
    for (int kc = 0; kc < 2; ++kc)
#pragma unroll
      for (int m = 0; m < 4; ++m)
#pragma unroll
        for (int n = 0; n < 4; ++n)
          MFMA16(acc[m][n + 4], aq[m][kc], bq[n][kc]);
    PRIO(0);
    BAR();  // all waves done reading tile t
    if (t + 1 < KT) {
      stageA128(Ap, K, t + 1, sa, tid);
      stageB256(Bp, K, t + 1, sb, tid);
      VMCNT0();  // staged tile complete (other resident block computes meanwhile)
    }
    BAR();
  }
#undef LDA
#undef LDB
}

// ================= Mainloop variant B: 256x256, 512 thr, dbuf, clustered reads =================
// (best measured for the proj shape: ~85 us)
__device__ __forceinline__ void stage_half(const unsigned short* __restrict__ gp, int K,
                                           int kt, int half, char* lds_mat, int tid) {
#pragma unroll
  for (int it = 0; it < 2; ++it) {
    int li = half * 1024 + it * 512 + tid;  // 16B-chunk index in 256x64 tile
    int r = li >> 3, c = li & 7;
    int cs = c ^ (r & 7);
    GLOAD16(gp + (size_t)r * K + kt * 64 + cs * 8, lds_mat + li * 16);
  }
}

__device__ __forceinline__ void gemm256sq_mainloop(const unsigned short* __restrict__ Ap,
                                                   const unsigned short* __restrict__ Bp,
                                                   int K, int tid, char* smem,
                                                   f32x4 acc[8][4]) {
  char* sa = smem;           // A: 2 bufs x 32768 B
  char* sb = smem + 65536;   // B: 2 bufs x 32768 B
  const int KT = K >> 6;     // 32

  int wid = tid >> 6, lane = tid & 63;
  int wr = wid >> 2, wc = wid & 3;
  int lg = lane >> 4, l15 = lane & 15;
  int swz7 = l15 & 7;

#define LDA2(ab, m, kc) \
  (*(const short8*)((const unsigned short*)(ab) + (size_t)((wr * 128 + (m) * 16 + l15) * 64 + ((((kc) * 4 + lg) ^ swz7) * 8))))
#define LDB2(bb, n, kc) \
  (*(const short8*)((const unsigned short*)(bb) + (size_t)((wc * 64 + (n) * 16 + l15) * 64 + ((((kc) * 4 + lg) ^ swz7) * 8))))

  stage_half(Bp, K, 0, 0, sb, tid);
  stage_half(Bp, K, 0, 1, sb, tid);
  stage_half(Ap, K, 0, 0, sa, tid);
  stage_half(Ap, K, 0, 1, sa, tid);
  stage_half(Bp, K, 1, 0, sb + 32768, tid);
  stage_half(Bp, K, 1, 1, sb + 32768, tid);
  stage_half(Ap, K, 1, 0, sa + 32768, tid);
  stage_half(Ap, K, 1, 1, sa + 32768, tid);
  VMCNT8();
  BAR();

  for (int t = 0; t < KT; ++t) {
    int p = t & 1;
    const char* ab = sa + p * 32768;
    const char* bb = sb + p * 32768;
    int kt2 = (t + 2 < KT) ? t + 2 : KT - 1;

    short8 bq01[2][2], bq23[2][2], aq[4][2], aq2[4][2];
#pragma unroll
    for (int n = 0; n < 2; ++n) { bq01[n][0] = LDB2(bb, n, 0); bq01[n][1] = LDB2(bb, n, 1); }
#pragma unroll
    for (int m = 0; m < 4; ++m) { aq[m][0] = LDA2(ab, m, 0); aq[m][1] = LDA2(ab, m, 1); }
#pragma unroll
    for (int n = 0; n < 2; ++n) { bq23[n][0] = LDB2(bb, n + 2, 0); bq23[n][1] = LDB2(bb, n + 2, 1); }
#pragma unroll
    for (int m = 0; m < 4; ++m) { aq2[m][0] = LDA2(ab, m + 4, 0); aq2[m][1] = LDA2(ab, m + 4, 1); }

    LGKMC(12);
    PRIO(1);
#pragma unroll
    for (int kc = 0; kc < 2; ++kc)
#pragma unroll
      for (int m = 0; m < 4; ++m)
#pragma unroll
        for (int n = 0; n < 2; ++n)
          MFMA16(acc[m][n], aq[m][kc], bq01[n][kc]);
    PRIO(0);

    LGKMC(8);
    BAR();
    stage_half(Bp, K, kt2, 0, sb + p * 32768, tid);
    stage_half(Bp, K, kt2, 1, sb + p * 32768, tid);

    PRIO(1);
#pragma unroll
    for (int kc = 0; kc < 2; ++kc)
#pragma unroll
      for (int m = 0; m < 4; ++m)
#pragma unroll
        for (int n = 0; n < 2; ++n)
          MFMA16(acc[m][n + 2], aq[m][kc], bq23[n][kc]);
    PRIO(0);

    LGKMC(0);
    PRIO(1);
#pragma unroll
    for (int kc = 0; kc < 2; ++kc)
#pragma unroll
      for (int m = 0; m < 4; ++m)
#pragma unroll
        for (int n = 0; n < 2; ++n)
          MFMA16(acc[m + 4][n + 2], aq2[m][kc], bq23[n][kc]);
    PRIO(0);

    BAR();
    stage_half(Ap, K, kt2, 0, sa + p * 32768, tid);
    stage_half(Ap, K, kt2, 1, sa + p * 32768, tid);
    PRIO(1);
#pragma unroll
    for (int kc = 0; kc < 2; ++kc)
#pragma unroll
      for (int m = 0; m < 4; ++m)
#pragma unroll
        for (int n = 0; n < 2; ++n)
          MFMA16(acc[m + 4][n], aq2[m][kc], bq01[n][kc]);
    PRIO(0);
    VMCNT8();
    BAR();
  }
#undef LDA2
#undef LDB2
}

// ---------------- QKV GEMM 128x256 (variant A): q/k + v^T via LDS for coalesced stores ----------------
__global__ __launch_bounds__(256, 2) void gemm_qkv256_kernel(const unsigned short* __restrict__ A,
                                                             const unsigned short* __restrict__ Bt,
                                                             const float* __restrict__ bias,
                                                             unsigned short* __restrict__ qb,
                                                             unsigned short* __restrict__ kb,
                                                             unsigned short* __restrict__ vtb) {
  extern __shared__ char smem[];
  int wg = blockIdx.x;                 // 1536 blocks
  int xcd = wg & 7, idx = wg >> 3;     // 192 per XCD
  int bn = xcd * 3 + idx % 3;          // 3 bn (256-col units) per XCD -> B panels L2-resident
  int bm = idx / 3;                    // 0..63 (128-row units)
  int tid = threadIdx.x;

  f32x4 acc[4][8];
  f32x4 zero = {0.f, 0.f, 0.f, 0.f};
#pragma unroll
  for (int m = 0; m < 4; ++m)
#pragma unroll
    for (int n = 0; n < 8; ++n) acc[m][n] = zero;

  gemm128x256_mainloop(A + (size_t)bm * 128 * 2048, Bt + (size_t)bn * 256 * 2048, 2048, tid, smem, acc);

  const float QSCALE = (float)(0.08838834764831845 * 1.4426950408889634);  // D^-0.5 * log2(e)
  int wid = tid >> 6, lane = tid & 63;
  int wr = wid >> 1, wc = wid & 1, lg = lane >> 4, l15 = lane & 15;

  if (bn >= 16) {
    // ---- v-block: col-major LDS [dloc 0..255][t 0..127], write [bh][d][t] coalesced ----
    int h0v = (bn - 16) * 2;
#pragma unroll
    for (int n = 0; n < 8; ++n) {
      int cl = wc * 128 + n * 16 + l15;  // 0..255 (= dloc)
      float bv = bias[bn * 256 + cl];
#pragma unroll
      for (int m = 0; m < 4; ++m) {
        int rl = wr * 64 + m * 16 + lg * 4;  // 0..124
        unsigned int w0 = cvtpk(acc[m][n][0] + bv, acc[m][n][1] + bv);
        unsigned int w1 = cvtpk(acc[m][n][2] + bv, acc[m][n][3] + bv);
        uint2v pk = {w0, w1};
        *(uint2v*)(smem + cl * 256 + ((rl * 2) ^ ((cl & 7) << 4))) = pk;
      }
    }
    LGKM0();
    BAR();
    int b = (bm * 128) >> 11, t0 = (bm * 128) & 2047;
#pragma unroll
    for (int i = 0; i < 16; ++i) {
      int id = i * 256 + tid;          // 4096 chunks
      int dloc = id >> 4, c = id & 15; // dloc 0..255, 16B-chunk 0..15
      short8 v = *(const short8*)(smem + dloc * 256 + ((c * 16) ^ ((dloc & 7) << 4)));
      int bh_ = b * 16 + h0v + (dloc >> 7);
      int d = dloc & 127;
      *(short8*)(vtb + ((size_t)bh_ * 128 + d) * 2048 + t0 + c * 8) = v;
    }
  } else {
    // ---- q/k block: row-major LDS [rl 0..127][cl 0..255], coalesced [bh][t][d] stores ----
    bool isq = (bn < 8);
#pragma unroll
    for (int n = 0; n < 8; ++n) {
      int cl = wc * 128 + n * 16 + l15;
      float bv = bias[bn * 256 + cl];
#pragma unroll
      for (int m = 0; m < 4; ++m) {
#pragma unroll
        for (int g = 0; g < 4; ++g) {
          int rl = wr * 64 + m * 16 + lg * 4 + g;  // 0..127
          float r = acc[m][n][g] + bv;
          if (isq) r *= QSCALE;
          *(unsigned short*)(smem + rl * 512 + ((cl * 2) ^ ((rl & 15) << 4))) = f2bf(r);
        }
      }
    }
    LGKM0();
    BAR();
    unsigned short* dst = isq ? qb : kb;
    int h0 = (bn & 7) * 2;
#pragma unroll
    for (int i = 0; i < 16; ++i) {
      int id = i * 256 + tid;          // 4096 chunks
      int rl = id >> 5, c8 = id & 31;  // row 0..127, chunk 0..31
      short8 v = *(const short8*)(smem + rl * 512 + ((c8 * 16) ^ ((rl & 15) << 4)));
      int row = bm * 128 + rl;
      int b = row >> 11, t = row & 2047;
      int h = h0 + (c8 >> 4);
      int d0 = (c8 & 15) * 8;
      *(short8*)(dst + ((size_t)(b * 16 + h) * 2048 + t) * 128 + d0) = v;
    }
  }
}

// ---------------- Proj GEMM 256x256 (variant B): fp32 output + bias ----------------
__global__ __launch_bounds__(512, 2) void gemm_proj256_kernel(const unsigned short* __restrict__ A,
                                                              const unsigned short* __restrict__ Bt,
                                                              const float* __restrict__ bias,
                                                              float* __restrict__ out) {
  extern __shared__ char smem[];
  int wg = blockIdx.x;            // 256 blocks
  int bm = wg >> 3, bn = wg & 7;  // one bn column per XCD; B-panel L2-resident
  int tid = threadIdx.x;

  f32x4 acc[8][4];
  f32x4 zero = {0.f, 0.f, 0.f, 0.f};
#pragma unroll
  for (int m = 0; m < 8; ++m)
#pragma unroll
    for (int n = 0; n < 4; ++n) acc[m][n] = zero;

  gemm256sq_mainloop(A + (size_t)bm * 256 * 2048, Bt + (size_t)bn * 256 * 2048, 2048, tid, smem, acc);

  int wid = tid >> 6, lane = tid & 63;
  int wr = wid >> 2, wc = wid & 3, lg = lane >> 4, l15 = lane & 15;
#pragma unroll
  for (int n = 0; n < 4; ++n) {
    int col = bn * 256 + wc * 64 + n * 16 + l15;
    float bv = bias[col];
#pragma unroll
    for (int m = 0; m < 8; ++m) {
#pragma unroll
      for (int g = 0; g < 4; ++g) {
        int row = bm * 256 + wr * 128 + m * 16 + lg * 4 + g;
        out[(size_t)row * 2048 + col] = acc[m][n][g] + bv;
      }
    }
  }
}

// ---------------- Flash attention: QBLK=256 (8 waves x 32 rows), paired q-tiles, dbuf K/V ----------------
__global__ __launch_bounds__(512) void attn_kernel(const unsigned short* __restrict__ qb,
                                                   const unsigned short* __restrict__ kb,
                                                   const unsigned short* __restrict__ vtb,
                                                   unsigned short* __restrict__ ob) {
  extern __shared__ char asmem[];
  int bh = blockIdx.x;     // 0..63 (same-XCD sharers for K/V L2 locality)
  int pairi = blockIdx.y;  // 0..3
  int b = bh >> 4, h = bh & 15;
  int tid = threadIdx.x, wid = tid >> 6, lane = tid & 63;
  int l31 = lane & 31, hi = lane >> 5;

  const unsigned short* Q  = qb  + (size_t)bh * 2048 * 128;
  const unsigned short* K  = kb  + (size_t)bh * 2048 * 128;
  const unsigned short* Vt = vtb + (size_t)bh * 128 * 2048;

#pragma unroll 1
  for (int pass = 0; pass < 2; ++pass) {
    int qt = pass == 0 ? (7 - pairi) : pairi;   // 256-row q-tile
    int NT = 4 * qt + 4;
    int qbase = qt * 256 + wid * 32;
    int qrow = qbase + l31;

    short8 qf[8];
#pragma unroll
    for (int kc = 0; kc < 8; ++kc)
      qf[kc] = *(const short8*)(Q + (size_t)qrow * 128 + kc * 16 + hi * 8);

    f32x16 o0 = {}, o1 = {}, o2 = {}, o3 = {};  // O^T[d][q=l31]
    float m_run = -1e30f, l_run = 0.f;

    {
      char* kb_ = asmem;
#pragma unroll
      for (int it = 0; it < 2; ++it) {
        int li = it * 512 + tid;
        int r = li >> 4, c = li & 15;
        GLOAD16(K + (size_t)r * 128 + (c ^ (r & 7)) * 8, kb_ + li * 16);
      }
#pragma unroll
      for (int it = 0; it < 2; ++it) {
        int li = it * 512 + tid;
        int r = li >> 3, c = li & 7;
        GLOAD16(Vt + (size_t)r * 2048 + (c ^ (r & 7)) * 8, kb_ + 16384 + li * 16);
      }
    }
    VMCNT0();
    BAR();

#pragma unroll 1
    for (int kt = 0; kt < NT; ++kt) {
      char* cb = asmem + ((kt & 1) << 15);
      if (kt + 1 < NT) {
        char* nb = asmem + (((kt + 1) & 1) << 15);
        int kt1 = kt + 1;
#pragma unroll
        for (int it = 0; it < 2; ++it) {
          int li = it * 512 + tid;
          int r = li >> 4, c = li & 15;
          GLOAD16(K + (size_t)(kt1 * 64 + r) * 128 + (c ^ (r & 7)) * 8, nb + li * 16);
        }
#pragma unroll
        for (int it = 0; it < 2; ++it) {
          int li = it * 512 + tid;
          int r = li >> 3, c = li & 7;
          GLOAD16(Vt + (size_t)r * 2048 + kt1 * 64 + (c ^ (r & 7)) * 8, nb + 16384 + li * 16);
        }
      }

      bool active = (kt * 64 <= qbase + 31);  // wave-uniform
      if (active) {
        const char* k_l = cb;
        const char* v_l = cb + 16384;

        f32x16 s0v = {}, s1v = {};
        PRIO(1);
#pragma unroll
        for (int kc = 0; kc < 8; ++kc) {
          int cg = kc * 2 + hi;
          int sw = l31 & 7;
          short8 kf0 = *(const short8*)(k_l + l31 * 256 + ((cg ^ sw) * 16));
          s0v = __builtin_amdgcn_mfma_f32_32x32x16_bf16(kf0, qf[kc], s0v, 0, 0, 0);
          short8 kf1 = *(const short8*)(k_l + (32 + l31) * 256 + ((cg ^ sw) * 16));
          s1v = __builtin_amdgcn_mfma_f32_32x32x16_bf16(kf1, qf[kc], s1v, 0, 0, 0);
        }
        PRIO(0);

        if (kt * 64 + 63 > qbase) {
          int kvb = kt * 64 + 4 * hi;
#pragma unroll
          for (int r = 0; r < 16; ++r) {
            int kv = kvb + (r & 3) + 8 * (r >> 2);
            if (kv > qrow) s0v[r] = -1e30f;
            if (kv + 32 > qrow) s1v[r] = -1e30f;
          }
        }

        float tmax[16];
#pragma unroll
        for (int i = 0; i < 16; ++i) tmax[i] = fmaxf(s0v[i], s1v[i]);
#pragma unroll
        for (int st = 8; st >= 1; st >>= 1)
#pragma unroll
          for (int i = 0; i < st; ++i) tmax[i] = fmaxf(tmax[i], tmax[i + st]);
        float pmax = fmaxf(tmax[0], __shfl_xor(tmax[0], 32));

        if (!__all(pmax <= m_run + 8.0f)) {
          float mn = fmaxf(m_run, pmax);
          float alpha = exp2f(m_run - mn);
          m_run = mn; l_run *= alpha;
          o0 *= alpha; o1 *= alpha; o2 *= alpha; o3 *= alpha;
        }

#pragma unroll
        for (int i = 0; i < 16; ++i) {
          s0v[i] = exp2f(s0v[i] - m_run);
          s1v[i] = exp2f(s1v[i] - m_run);
        }
        float tsum[16];
#pragma unroll
        for (int i = 0; i < 16; ++i) tsum[i] = s0v[i] + s1v[i];
#pragma unroll
        for (int st = 8; st >= 1; st >>= 1)
#pragma unroll
          for (int i = 0; i < st; ++i) tsum[i] += tsum[i + st];
        float rsum = tsum[0] + __shfl_xor(tsum[0], 32);
        l_run += rsum;

#define BUILD_PA(sv, base, out)                                                \
        {                                                                      \
          unsigned int a_ = cvtpk(sv[base + 0], sv[base + 1]);                 \
          unsigned int c_ = cvtpk(sv[base + 2], sv[base + 3]);                 \
          unsigned int b_ = cvtpk(sv[base + 4], sv[base + 5]);                 \
          unsigned int d_ = cvtpk(sv[base + 6], sv[base + 7]);                 \
          uint2v r0_ = __builtin_amdgcn_permlane32_swap(a_, b_, false, false); \
          uint2v r1_ = __builtin_amdgcn_permlane32_swap(c_, d_, false, false); \
          union { unsigned int u[4]; short8 v; } uu_;                          \
          uu_.u[0] = r0_[0]; uu_.u[1] = r1_[0]; uu_.u[2] = r0_[1]; uu_.u[3] = r1_[1]; \
          out = uu_.v;                                                         \
        }
        short8 pa0, pa1, pa2, pa3;
        BUILD_PA(s0v, 0, pa0);
        BUILD_PA(s0v, 8, pa1);
        BUILD_PA(s1v, 0, pa2);
        BUILD_PA(s1v, 8, pa3);
#undef BUILD_PA

        PRIO(1);
#define PV_STEP(ovar, dt)                                                          \
        {                                                                          \
          int rv_ = dt * 32 + l31;                                                 \
          const char* vb_ = v_l + rv_ * 128;                                       \
          int sw_ = rv_ & 7;                                                       \
          short8 v0_ = *(const short8*)(vb_ + (((0 + hi) ^ sw_) * 16));            \
          ovar = __builtin_amdgcn_mfma_f32_32x32x16_bf16(v0_, pa0, ovar, 0, 0, 0); \
          short8 v1_ = *(const short8*)(vb_ + (((2 + hi) ^ sw_) * 16));            \
          ovar = __builtin_amdgcn_mfma_f32_32x32x16_bf16(v1_, pa1, ovar, 0, 0, 0); \
          short8 v2_ = *(const short8*)(vb_ + (((4 + hi) ^ sw_) * 16));            \
          ovar = __builtin_amdgcn_mfma_f32_32x32x16_bf16(v2_, pa2, ovar, 0, 0, 0); \
          short8 v3_ = *(const short8*)(vb_ + (((6 + hi) ^ sw_) * 16));            \
          ovar = __builtin_amdgcn_mfma_f32_32x32x16_bf16(v3_, pa3, ovar, 0, 0, 0); \
        }
        PV_STEP(o0, 0)
        PV_STEP(o1, 1)
        PV_STEP(o2, 2)
        PV_STEP(o3, 3)
#undef PV_STEP
        PRIO(0);
      }

      VMCNT0();
      BAR();
    }

    float inv = 1.0f / l_run;
    size_t orow = (size_t)(b * 2048 + qt * 256 + wid * 32 + l31);
    unsigned short* ob_p = ob + orow * 2048 + h * 128;
#define STORE_DT(ovar, dt)                                                         \
    {                                                                              \
      _Pragma("unroll")                                                            \
      for (int rq = 0; rq < 4; ++rq) {                                             \
        unsigned int w0 = cvtpk(ovar[rq * 4 + 0] * inv, ovar[rq * 4 + 1] * inv);   \
        unsigned int w1 = cvtpk(ovar[rq * 4 + 2] * inv, ovar[rq * 4 + 3] * inv);   \
        uint2v st = {w0, w1};                                                      \
        *(uint2v*)(ob_p + dt * 32 + rq * 8 + 4 * hi) = st;                         \
      }                                                                            \
    }
    STORE_DT(o0, 0)
    STORE_DT(o1, 1)
    STORE_DT(o2, 2)
    STORE_DT(o3, 3)
#undef STORE_DT
  }
}

// ---------------- launch ----------------
extern "C" void kernel_launch(void* const* d_in, const int* in_sizes, int n_in,
                              void* d_out, int out_size, void* d_ws, size_t ws_size,
                              hipStream_t stream) {
  const float* x     = (const float*)d_in[0];
  const float* Wqkv  = (const float*)d_in[1];
  const float* bqkv  = (const float*)d_in[2];
  const float* Wproj = (const float*)d_in[3];
  const float* bproj = (const float*)d_in[4];
  float* out = (float*)d_out;

  char* ws = (char*)d_ws;
  unsigned short* x_bf   = (unsigned short*)ws;                         // 32MB, reused as attn_out
  unsigned short* wqkvt  = (unsigned short*)(ws + 33554432);            // 24MB
  unsigned short* wprojt = (unsigned short*)(ws + 33554432 + 25165824); // 8MB
  unsigned short* qb     = (unsigned short*)(ws + 67108864);            // 32MB (pre-scaled)
  unsigned short* kb     = (unsigned short*)(ws + 100663296);           // 32MB
  unsigned short* vtb    = (unsigned short*)(ws + 134217728);           // 32MB [bh][d][t]

  (void)hipFuncSetAttribute((const void*)gemm_qkv256_kernel,
                            hipFuncAttributeMaxDynamicSharedMemorySize, 65536);
  (void)hipFuncSetAttribute((const void*)gemm_proj256_kernel,
                            hipFuncAttributeMaxDynamicSharedMemorySize, 131072);
  (void)hipFuncSetAttribute((const void*)attn_kernel,
                            hipFuncAttributeMaxDynamicSharedMemorySize, 65536);

  cast_bf16_kernel<<<16384, 256, 0, stream>>>(x, x_bf);
  transpose_cast_kernel<<<dim3(192, 64), dim3(32, 8), 0, stream>>>(Wqkv, wqkvt, 2048, 6144);
  transpose_cast_kernel<<<dim3(64, 64), dim3(32, 8), 0, stream>>>(Wproj, wprojt, 2048, 2048);
  gemm_qkv256_kernel<<<1536, 256, 65536, stream>>>(x_bf, wqkvt, bqkv, qb, kb, vtb);
  attn_kernel<<<dim3(64, 4), 512, 65536, stream>>>(qb, kb, vtb, x_bf /* attn_out */);
  gemm_proj256_kernel<<<256, 512, 131072, stream>>>(x_bf, wprojt, bproj, out);
}

// Round 18
// 389.541 us; speedup vs baseline: 1.0210x; 1.0076x over previous
//
#include <hip/hip_runtime.h>
#include <hip/hip_bf16.h>
#include <stdint.h>

typedef __attribute__((ext_vector_type(8))) short short8;
typedef __attribute__((ext_vector_type(4))) float f32x4;
typedef __attribute__((ext_vector_type(16))) float f32x16;
typedef __attribute__((ext_vector_type(2))) unsigned int uint2v;

__device__ __forceinline__ unsigned short f2bf(float f) {
  union { float f; unsigned int u; } v; v.f = f;
  unsigned int r = v.u + 0x7FFFu + ((v.u >> 16) & 1u);
  return (unsigned short)(r >> 16);
}

__device__ __forceinline__ unsigned int cvtpk(float lo, float hi) {
  unsigned int r;
  asm("v_cvt_pk_bf16_f32 %0, %1, %2" : "=v"(r) : "v"(lo), "v"(hi));
  return r;
}

#define GLOAD16(gsrc, ldst)                                                                  \
  __builtin_amdgcn_global_load_lds((const __attribute__((address_space(1))) void*)(gsrc),    \
                                   (__attribute__((address_space(3))) void*)(ldst), 16, 0, 0)

#define BAR() __builtin_amdgcn_s_barrier()
#define LGKMC(n) do { asm volatile("s_waitcnt lgkmcnt(" #n ")" ::: "memory"); \
                      __builtin_amdgcn_sched_barrier(0); } while (0)
#define LGKM0() LGKMC(0)
#define VMCNT0() asm volatile("s_waitcnt vmcnt(0)" ::: "memory")
#define VMCNT8() do { asm volatile("s_waitcnt vmcnt(8)" ::: "memory"); \
                      __builtin_amdgcn_sched_barrier(0); } while (0)
#define PRIO(x) __builtin_amdgcn_s_setprio(x)
#define MFMA16(d, a, b) d = __builtin_amdgcn_mfma_f32_16x16x32_bf16(a, b, d, 0, 0, 0)

// ---------------- merged preprocessing: cast x + transpose-cast Wqkv + Wproj ----------------
// blocks [0,16384): cast x (4 fp32/thread); [16384,28672): Wqkv transpose (32x32 tiles);
// [28672,32768): Wproj transpose. One launch instead of three.
__global__ __launch_bounds__(256) void preproc_kernel(const float* __restrict__ x,
                                                      const float* __restrict__ Wqkv,
                                                      const float* __restrict__ Wproj,
                                                      unsigned short* __restrict__ x_bf,
                                                      unsigned short* __restrict__ wqkvt,
                                                      unsigned short* __restrict__ wprojt) {
  __shared__ float tile[32][33];
  int blk = blockIdx.x;
  int tid = threadIdx.x;
  if (blk < 16384) {
    int i = blk * 256 + tid;
    float4 v = ((const float4*)x)[i];
    ushort4 o;
    o.x = f2bf(v.x); o.y = f2bf(v.y); o.z = f2bf(v.z); o.w = f2bf(v.w);
    ((ushort4*)x_bf)[i] = o;
    return;
  }
  const float* W;
  unsigned short* Wt;
  int n0, k0, N;
  if (blk < 16384 + 12288) {
    int b = blk - 16384;
    W = Wqkv; Wt = wqkvt; N = 6144;
    n0 = (b % 192) * 32; k0 = (b / 192) * 32;
  } else {
    int b = blk - 16384 - 12288;
    W = Wproj; Wt = wprojt; N = 2048;
    n0 = (b & 63) * 32; k0 = (b >> 6) * 32;
  }
  int tx = tid & 31, ty = tid >> 5;  // 32 x 8
#pragma unroll
  for (int j = 0; j < 32; j += 8)
    tile[ty + j][tx] = W[(size_t)(k0 + ty + j) * N + n0 + tx];
  __syncthreads();
#pragma unroll
  for (int j = 0; j < 32; j += 8)
    Wt[(size_t)(n0 + ty + j) * 2048 + k0 + tx] = f2bf(tile[tx][ty + j]);
}

// ================= Mainloop variant A: 128x256, 256 thr, single-buffer, 2 blocks/CU =================
__device__ __forceinline__ void stageA128(const unsigned short* __restrict__ gp, int K,
                                          int kt, char* lds, int tid) {
#pragma unroll
  for (int it = 0; it < 4; ++it) {
    int li = it * 256 + tid;  // 0..1023 chunks of 16B (128 rows x 8 chunks)
    int r = li >> 3, c = li & 7;
    GLOAD16(gp + (size_t)r * K + kt * 64 + (c ^ (r & 7)) * 8, lds + li * 16);
  }
}
__device__ __forceinline__ void stageB256(const unsigned short* __restrict__ gp, int K,
                                          int kt, char* lds, int tid) {
#pragma unroll
  for (int it = 0; it < 8; ++it) {
    int li = it * 256 + tid;  // 0..2047 chunks (256 rows x 8 chunks)
    int r = li >> 3, c = li & 7;
    GLOAD16(gp + (size_t)r * K + kt * 64 + (c ^ (r & 7)) * 8, lds + li * 16);
  }
}

__device__ __forceinline__ void gemm128x256_mainloop(const unsigned short* __restrict__ Ap,
                                                     const unsigned short* __restrict__ Bp,
                                                     int K, int tid, char* smem,
                                                     f32x4 acc[4][8]) {
  char* sa = smem;           // 16 KB
  char* sb = smem + 16384;   // 32 KB
  const int KT = K >> 6;     // 32

  int wid = tid >> 6, lane = tid & 63;
  int wr = wid >> 1, wc = wid & 1;
  int lg = lane >> 4, l15 = lane & 15;
  int swz7 = l15 & 7;

#define LDA(m, kc) \
  (*(const short8*)((const unsigned short*)sa + (size_t)((wr * 64 + (m) * 16 + l15) * 64 + ((((kc) * 4 + lg) ^ swz7) * 8))))
#define LDB(n, kc) \
  (*(const short8*)((const unsigned short*)sb + (size_t)((wc * 128 + (n) * 16 + l15) * 64 + ((((kc) * 4 + lg) ^ swz7) * 8))))

  stageA128(Ap, K, 0, sa, tid);
  stageB256(Bp, K, 0, sb, tid);
  VMCNT0();
  BAR();

  for (int t = 0; t < KT; ++t) {
    short8 aq[4][2], bq[4][2];
#pragma unroll
    for (int m = 0; m < 4; ++m) { aq[m][0] = LDA(m, 0); aq[m][1] = LDA(m, 1); }
#pragma unroll
    for (int n = 0; n < 4; ++n) { bq[n][0] = LDB(n, 0); bq[n][1] = LDB(n, 1); }
    LGKM0();
    PRIO(1);
#pragma unroll
    for (int kc = 0; kc < 2; ++kc)
#pragma unroll
      for (int m = 0; m < 4; ++m)
#pragma unroll
        for (int n = 0; n < 4; ++n)
          MFMA16(acc[m][n], aq[m][kc], bq[n][kc]);
    PRIO(0);
#pragma unroll
    for (int n = 0; n < 4; ++n) { bq[n][0] = LDB(n + 4, 0); bq[n][1] = LDB(n + 4, 1); }
    LGKM0();
    PRIO(1);
#pragma unroll
    for (int kc = 0; kc < 2; ++kc)
#pragma unroll
      for (int m = 0; m < 4; ++m)
#pragma unroll
        for (int n = 0; n < 4; ++n)
          MFMA16(acc[m][n + 4], aq[m][kc], bq[n][kc]);
    PRIO(0);
    BAR();  // all waves done reading tile t
    if (t + 1 < KT) {
      stageA128(Ap, K, t + 1, sa, tid);
      stageB256(Bp, K, t + 1, sb, tid);
      VMCNT0();  // staged tile complete (other resident block computes meanwhile)
    }
    BAR();
  }
#undef LDA
#undef LDB
}

// ================= Mainloop variant B: 256x256, 512 thr, dbuf, clustered reads =================
__device__ __forceinline__ void stage_half(const unsigned short* __restrict__ gp, int K,
                                           int kt, int half, char* lds_mat, int tid) {
#pragma unroll
  for (int it = 0; it < 2; ++it) {
    int li = half * 1024 + it * 512 + tid;  // 16B-chunk index in 256x64 tile
    int r = li >> 3, c = li & 7;
    int cs = c ^ (r & 7);
    GLOAD16(gp + (size_t)r * K + kt * 64 + cs * 8, lds_mat + li * 16);
  }
}

__device__ __forceinline__ void gemm256sq_mainloop(const unsigned short* __restrict__ Ap,
                                                   const unsigned short* __restrict__ Bp,
                                                   int K, int tid, char* smem,
                                                   f32x4 acc[8][4]) {
  char* sa = smem;           // A: 2 bufs x 32768 B
  char* sb = smem + 65536;   // B: 2 bufs x 32768 B
  const int KT = K >> 6;     // 32

  int wid = tid >> 6, lane = tid & 63;
  int wr = wid >> 2, wc = wid & 3;
  int lg = lane >> 4, l15 = lane & 15;
  int swz7 = l15 & 7;

#define LDA2(ab, m, kc) \
  (*(const short8*)((const unsigned short*)(ab) + (size_t)((wr * 128 + (m) * 16 + l15) * 64 + ((((kc) * 4 + lg) ^ swz7) * 8))))
#define LDB2(bb, n, kc) \
  (*(const short8*)((const unsigned short*)(bb) + (size_t)((wc * 64 + (n) * 16 + l15) * 64 + ((((kc) * 4 + lg) ^ swz7) * 8))))

  stage_half(Bp, K, 0, 0, sb, tid);
  stage_half(Bp, K, 0, 1, sb, tid);
  stage_half(Ap, K, 0, 0, sa, tid);
  stage_half(Ap, K, 0, 1, sa, tid);
  stage_half(Bp, K, 1, 0, sb + 32768, tid);
  stage_half(Bp, K, 1, 1, sb + 32768, tid);
  stage_half(Ap, K, 1, 0, sa + 32768, tid);
  stage_half(Ap, K, 1, 1, sa + 32768, tid);
  VMCNT8();
  BAR();

  for (int t = 0; t < KT; ++t) {
    int p = t & 1;
    const char* ab = sa + p * 32768;
    const char* bb = sb + p * 32768;
    int kt2 = (t + 2 < KT) ? t + 2 : KT - 1;

    short8 bq01[2][2], bq23[2][2], aq[4][2], aq2[4][2];
#pragma unroll
    for (int n = 0; n < 2; ++n) { bq01[n][0] = LDB2(bb, n, 0); bq01[n][1] = LDB2(bb, n, 1); }
#pragma unroll
    for (int m = 0; m < 4; ++m) { aq[m][0] = LDA2(ab, m, 0); aq[m][1] = LDA2(ab, m, 1); }
#pragma unroll
    for (int n = 0; n < 2; ++n) { bq23[n][0] = LDB2(bb, n + 2, 0); bq23[n][1] = LDB2(bb, n + 2, 1); }
#pragma unroll
    for (int m = 0; m < 4; ++m) { aq2[m][0] = LDA2(ab, m + 4, 0); aq2[m][1] = LDA2(ab, m + 4, 1); }

    LGKMC(12);
    PRIO(1);
#pragma unroll
    for (int kc = 0; kc < 2; ++kc)
#pragma unroll
      for (int m = 0; m < 4; ++m)
#pragma unroll
        for (int n = 0; n < 2; ++n)
          MFMA16(acc[m][n], aq[m][kc], bq01[n][kc]);
    PRIO(0);

    LGKMC(8);
    BAR();
    stage_half(Bp, K, kt2, 0, sb + p * 32768, tid);
    stage_half(Bp, K, kt2, 1, sb + p * 32768, tid);

    PRIO(1);
#pragma unroll
    for (int kc = 0; kc < 2; ++kc)
#pragma unroll
      for (int m = 0; m < 4; ++m)
#pragma unroll
        for (int n = 0; n < 2; ++n)
          MFMA16(acc[m][n + 2], aq[m][kc], bq23[n][kc]);
    PRIO(0);

    LGKMC(0);
    PRIO(1);
#pragma unroll
    for (int kc = 0; kc < 2; ++kc)
#pragma unroll
      for (int m = 0; m < 4; ++m)
#pragma unroll
        for (int n = 0; n < 2; ++n)
          MFMA16(acc[m + 4][n + 2], aq2[m][kc], bq23[n][kc]);
    PRIO(0);

    BAR();
    stage_half(Ap, K, kt2, 0, sa + p * 32768, tid);
    stage_half(Ap, K, kt2, 1, sa + p * 32768, tid);
    PRIO(1);
#pragma unroll
    for (int kc = 0; kc < 2; ++kc)
#pragma unroll
      for (int m = 0; m < 4; ++m)
#pragma unroll
        for (int n = 0; n < 2; ++n)
          MFMA16(acc[m + 4][n], aq2[m][kc], bq01[n][kc]);
    PRIO(0);
    VMCNT8();
    BAR();
  }
#undef LDA2
#undef LDB2
}

// ---------------- QKV GEMM 128x256 (variant A): q/k + v^T via LDS for coalesced stores ----------------
__global__ __launch_bounds__(256, 2) void gemm_qkv256_kernel(const unsigned short* __restrict__ A,
                                                             const unsigned short* __restrict__ Bt,
                                                             const float* __restrict__ bias,
                                                             unsigned short* __restrict__ qb,
                                                             unsigned short* __restrict__ kb,
                                                             unsigned short* __restrict__ vtb) {
  extern __shared__ char smem[];
  int wg = blockIdx.x;                 // 1536 blocks
  int xcd = wg & 7, idx = wg >> 3;     // 192 per XCD
  int bn = xcd * 3 + idx % 3;          // 3 bn (256-col units) per XCD -> B panels L2-resident
  int bm = idx / 3;                    // 0..63 (128-row units)
  int tid = threadIdx.x;

  f32x4 acc[4][8];
  f32x4 zero = {0.f, 0.f, 0.f, 0.f};
#pragma unroll
  for (int m = 0; m < 4; ++m)
#pragma unroll
    for (int n = 0; n < 8; ++n) acc[m][n] = zero;

  gemm128x256_mainloop(A + (size_t)bm * 128 * 2048, Bt + (size_t)bn * 256 * 2048, 2048, tid, smem, acc);

  const float QSCALE = (float)(0.08838834764831845 * 1.4426950408889634);  // D^-0.5 * log2(e)
  int wid = tid >> 6, lane = tid & 63;
  int wr = wid >> 1, wc = wid & 1, lg = lane >> 4, l15 = lane & 15;

  if (bn >= 16) {
    // ---- v-block: col-major LDS [dloc 0..255][t 0..127], write [bh][d][t] coalesced ----
    int h0v = (bn - 16) * 2;
#pragma unroll
    for (int n = 0; n < 8; ++n) {
      int cl = wc * 128 + n * 16 + l15;  // 0..255 (= dloc)
      float bv = bias[bn * 256 + cl];
#pragma unroll
      for (int m = 0; m < 4; ++m) {
        int rl = wr * 64 + m * 16 + lg * 4;  // 0..124
        unsigned int w0 = cvtpk(acc[m][n][0] + bv, acc[m][n][1] + bv);
        unsigned int w1 = cvtpk(acc[m][n][2] + bv, acc[m][n][3] + bv);
        uint2v pk = {w0, w1};
        *(uint2v*)(smem + cl * 256 + ((rl * 2) ^ ((cl & 7) << 4))) = pk;
      }
    }
    LGKM0();
    BAR();
    int b = (bm * 128) >> 11, t0 = (bm * 128) & 2047;
#pragma unroll
    for (int i = 0; i < 16; ++i) {
      int id = i * 256 + tid;          // 4096 chunks
      int dloc = id >> 4, c = id & 15; // dloc 0..255, 16B-chunk 0..15
      short8 v = *(const short8*)(smem + dloc * 256 + ((c * 16) ^ ((dloc & 7) << 4)));
      int bh_ = b * 16 + h0v + (dloc >> 7);
      int d = dloc & 127;
      *(short8*)(vtb + ((size_t)bh_ * 128 + d) * 2048 + t0 + c * 8) = v;
    }
  } else {
    // ---- q/k block: row-major LDS [rl 0..127][cl 0..255], coalesced [bh][t][d] stores ----
    bool isq = (bn < 8);
#pragma unroll
    for (int n = 0; n < 8; ++n) {
      int cl = wc * 128 + n * 16 + l15;
      float bv = bias[bn * 256 + cl];
#pragma unroll
      for (int m = 0; m < 4; ++m) {
#pragma unroll
        for (int g = 0; g < 4; ++g) {
          int rl = wr * 64 + m * 16 + lg * 4 + g;  // 0..127
          float r = acc[m][n][g] + bv;
          if (isq) r *= QSCALE;
          *(unsigned short*)(smem + rl * 512 + ((cl * 2) ^ ((rl & 15) << 4))) = f2bf(r);
        }
      }
    }
    LGKM0();
    BAR();
    unsigned short* dst = isq ? qb : kb;
    int h0 = (bn & 7) * 2;
#pragma unroll
    for (int i = 0; i < 16; ++i) {
      int id = i * 256 + tid;          // 4096 chunks
      int rl = id >> 5, c8 = id & 31;  // row 0..127, chunk 0..31
      short8 v = *(const short8*)(smem + rl * 512 + ((c8 * 16) ^ ((rl & 15) << 4)));
      int row = bm * 128 + rl;
      int b = row >> 11, t = row & 2047;
      int h = h0 + (c8 >> 4);
      int d0 = (c8 & 15) * 8;
      *(short8*)(dst + ((size_t)(b * 16 + h) * 2048 + t) * 128 + d0) = v;
    }
  }
}

// ---------------- Proj GEMM 256x256 (variant B): fp32 output + bias ----------------
__global__ __launch_bounds__(512, 2) void gemm_proj256_kernel(const unsigned short* __restrict__ A,
                                                              const unsigned short* __restrict__ Bt,
                                                              const float* __restrict__ bias,
                                                              float* __restrict__ out) {
  extern __shared__ char smem[];
  int wg = blockIdx.x;            // 256 blocks
  int bm = wg >> 3, bn = wg & 7;  // one bn column per XCD; B-panel L2-resident
  int tid = threadIdx.x;

  f32x4 acc[8][4];
  f32x4 zero = {0.f, 0.f, 0.f, 0.f};
#pragma unroll
  for (int m = 0; m < 8; ++m)
#pragma unroll
    for (int n = 0; n < 4; ++n) acc[m][n] = zero;

  gemm256sq_mainloop(A + (size_t)bm * 256 * 2048, Bt + (size_t)bn * 256 * 2048, 2048, tid, smem, acc);

  int wid = tid >> 6, lane = tid & 63;
  int wr = wid >> 2, wc = wid & 3, lg = lane >> 4, l15 = lane & 15;
#pragma unroll
  for (int n = 0; n < 4; ++n) {
    int col = bn * 256 + wc * 64 + n * 16 + l15;
    float bv = bias[col];
#pragma unroll
    for (int m = 0; m < 8; ++m) {
#pragma unroll
      for (int g = 0; g < 4; ++g) {
        int row = bm * 256 + wr * 128 + m * 16 + lg * 4 + g;
        out[(size_t)row * 2048 + col] = acc[m][n][g] + bv;
      }
    }
  }
}

// ---------------- Flash attention: QBLK=256 (8 waves x 32 rows), paired q-tiles, dbuf K/V ----------------
__global__ __launch_bounds__(512) void attn_kernel(const unsigned short* __restrict__ qb,
                                                   const unsigned short* __restrict__ kb,
                                                   const unsigned short* __restrict__ vtb,
                                                   unsigned short* __restrict__ ob) {
  extern __shared__ char asmem[];
  int bh = blockIdx.x;     // 0..63 (same-XCD sharers for K/V L2 locality)
  int pairi = blockIdx.y;  // 0..3
  int b = bh >> 4, h = bh & 15;
  int tid = threadIdx.x, wid = tid >> 6, lane = tid & 63;
  int l31 = lane & 31, hi = lane >> 5;

  const unsigned short* Q  = qb  + (size_t)bh * 2048 * 128;
  const unsigned short* K  = kb  + (size_t)bh * 2048 * 128;
  const unsigned short* Vt = vtb + (size_t)bh * 128 * 2048;

#pragma unroll 1
  for (int pass = 0; pass < 2; ++pass) {
    int qt = pass == 0 ? (7 - pairi) : pairi;   // 256-row q-tile
    int NT = 4 * qt + 4;
    int qbase = qt * 256 + wid * 32;
    int qrow = qbase + l31;

    short8 qf[8];
#pragma unroll
    for (int kc = 0; kc < 8; ++kc)
      qf[kc] = *(const short8*)(Q + (size_t)qrow * 128 + kc * 16 + hi * 8);

    f32x16 o0 = {}, o1 = {}, o2 = {}, o3 = {};  // O^T[d][q=l31]
    float m_run = -1e30f, l_run = 0.f;

    {
      char* kb_ = asmem;
#pragma unroll
      for (int it = 0; it < 2; ++it) {
        int li = it * 512 + tid;
        int r = li >> 4, c = li & 15;
        GLOAD16(K + (size_t)r * 128 + (c ^ (r & 7)) * 8, kb_ + li * 16);
      }
#pragma unroll
      for (int it = 0; it < 2; ++it) {
        int li = it * 512 + tid;
        int r = li >> 3, c = li & 7;
        GLOAD16(Vt + (size_t)r * 2048 + (c ^ (r & 7)) * 8, kb_ + 16384 + li * 16);
      }
    }
    VMCNT0();
    BAR();

#pragma unroll 1
    for (int kt = 0; kt < NT; ++kt) {
      char* cb = asmem + ((kt & 1) << 15);
      if (kt + 1 < NT) {
        char* nb = asmem + (((kt + 1) & 1) << 15);
        int kt1 = kt + 1;
#pragma unroll
        for (int it = 0; it < 2; ++it) {
          int li = it * 512 + tid;
          int r = li >> 4, c = li & 15;
          GLOAD16(K + (size_t)(kt1 * 64 + r) * 128 + (c ^ (r & 7)) * 8, nb + li * 16);
        }
#pragma unroll
        for (int it = 0; it < 2; ++it) {
          int li = it * 512 + tid;
          int r = li >> 3, c = li & 7;
          GLOAD16(Vt + (size_t)r * 2048 + kt1 * 64 + (c ^ (r & 7)) * 8, nb + 16384 + li * 16);
        }
      }

      bool active = (kt * 64 <= qbase + 31);  // wave-uniform
      if (active) {
        const char* k_l = cb;
        const char* v_l = cb + 16384;

        f32x16 s0v = {}, s1v = {};
        PRIO(1);
#pragma unroll
        for (int kc = 0; kc < 8; ++kc) {
          int cg = kc * 2 + hi;
          int sw = l31 & 7;
          short8 kf0 = *(const short8*)(k_l + l31 * 256 + ((cg ^ sw) * 16));
          s0v = __builtin_amdgcn_mfma_f32_32x32x16_bf16(kf0, qf[kc], s0v, 0, 0, 0);
          short8 kf1 = *(const short8*)(k_l + (32 + l31) * 256 + ((cg ^ sw) * 16));
          s1v = __builtin_amdgcn_mfma_f32_32x32x16_bf16(kf1, qf[kc], s1v, 0, 0, 0);
        }
        PRIO(0);

        if (kt * 64 + 63 > qbase) {
          int kvb = kt * 64 + 4 * hi;
#pragma unroll
          for (int r = 0; r < 16; ++r) {
            int kv = kvb + (r & 3) + 8 * (r >> 2);
            if (kv > qrow) s0v[r] = -1e30f;
            if (kv + 32 > qrow) s1v[r] = -1e30f;
          }
        }

        float tmax[16];
#pragma unroll
        for (int i = 0; i < 16; ++i) tmax[i] = fmaxf(s0v[i], s1v[i]);
#pragma unroll
        for (int st = 8; st >= 1; st >>= 1)
#pragma unroll
          for (int i = 0; i < st; ++i) tmax[i] = fmaxf(tmax[i], tmax[i + st]);
        float pmax = fmaxf(tmax[0], __shfl_xor(tmax[0], 32));

        if (!__all(pmax <= m_run + 8.0f)) {
          float mn = fmaxf(m_run, pmax);
          float alpha = exp2f(m_run - mn);
          m_run = mn; l_run *= alpha;
          o0 *= alpha; o1 *= alpha; o2 *= alpha; o3 *= alpha;
        }

#pragma unroll
        for (int i = 0; i < 16; ++i) {
          s0v[i] = exp2f(s0v[i] - m_run);
          s1v[i] = exp2f(s1v[i] - m_run);
        }
        float tsum[16];
#pragma unroll
        for (int i = 0; i < 16; ++i) tsum[i] = s0v[i] + s1v[i];
#pragma unroll
        for (int st = 8; st >= 1; st >>= 1)
#pragma unroll
          for (int i = 0; i < st; ++i) tsum[i] += tsum[i + st];
        float rsum = tsum[0] + __shfl_xor(tsum[0], 32);
        l_run += rsum;

#define BUILD_PA(sv, base, out)                                                \
        {                                                                      \
          unsigned int a_ = cvtpk(sv[base + 0], sv[base + 1]);                 \
          unsigned int c_ = cvtpk(sv[base + 2], sv[base + 3]);                 \
          unsigned int b_ = cvtpk(sv[base + 4], sv[base + 5]);                 \
          unsigned int d_ = cvtpk(sv[base + 6], sv[base + 7]);                 \
          uint2v r0_ = __builtin_amdgcn_permlane32_swap(a_, b_, false, false); \
          uint2v r1_ = __builtin_amdgcn_permlane32_swap(c_, d_, false, false); \
          union { unsigned int u[4]; short8 v; } uu_;                          \
          uu_.u[0] = r0_[0]; uu_.u[1] = r1_[0]; uu_.u[2] = r0_[1]; uu_.u[3] = r1_[1]; \
          out = uu_.v;                                                         \
        }
        short8 pa0, pa1, pa2, pa3;
        BUILD_PA(s0v, 0, pa0);
        BUILD_PA(s0v, 8, pa1);
        BUILD_PA(s1v, 0, pa2);
        BUILD_PA(s1v, 8, pa3);
#undef BUILD_PA

        PRIO(1);
#define PV_STEP(ovar, dt)                                                          \
        {                                                                          \
          int rv_ = dt * 32 + l31;                                                 \
          const char* vb_ = v_l + rv_ * 128;                                       \
          int sw_ = rv_ & 7;                                                       \
          short8 v0_ = *(const short8*)(vb_ + (((0 + hi) ^ sw_) * 16));            \
          ovar = __builtin_amdgcn_mfma_f32_32x32x16_bf16(v0_, pa0, ovar, 0, 0, 0); \
          short8 v1_ = *(const short8*)(vb_ + (((2 + hi) ^ sw_) * 16));            \
          ovar = __builtin_amdgcn_mfma_f32_32x32x16_bf16(v1_, pa1, ovar, 0, 0, 0); \
          short8 v2_ = *(const short8*)(vb_ + (((4 + hi) ^ sw_) * 16));            \
          ovar = __builtin_amdgcn_mfma_f32_32x32x16_bf16(v2_, pa2, ovar, 0, 0, 0); \
          short8 v3_ = *(const short8*)(vb_ + (((6 + hi) ^ sw_) * 16));            \
          ovar = __builtin_amdgcn_mfma_f32_32x32x16_bf16(v3_, pa3, ovar, 0, 0, 0); \
        }
        PV_STEP(o0, 0)
        PV_STEP(o1, 1)
        PV_STEP(o2, 2)
        PV_STEP(o3, 3)
#undef PV_STEP
        PRIO(0);
      }

      VMCNT0();
      BAR();
    }

    float inv = 1.0f / l_run;
    size_t orow = (size_t)(b * 2048 + qt * 256 + wid * 32 + l31);
    unsigned short* ob_p = ob + orow * 2048 + h * 128;
#define STORE_DT(ovar, dt)                                                         \
    {                                                                              \
      _Pragma("unroll")                                                            \
      for (int rq = 0; rq < 4; ++rq) {                                             \
        unsigned int w0 = cvtpk(ovar[rq * 4 + 0] * inv, ovar[rq * 4 + 1] * inv);   \
        unsigned int w1 = cvtpk(ovar[rq * 4 + 2] * inv, ovar[rq * 4 + 3] * inv);   \
        uint2v st = {w0, w1};                                                      \
        *(uint2v*)(ob_p + dt * 32 + rq * 8 + 4 * hi) = st;                         \
      }                                                                            \
    }
    STORE_DT(o0, 0)
    STORE_DT(o1, 1)
    STORE_DT(o2, 2)
    STORE_DT(o3, 3)
#undef STORE_DT
  }
}

// ---------------- launch ----------------
extern "C" void kernel_launch(void* const* d_in, const int* in_sizes, int n_in,
                              void* d_out, int out_size, void* d_ws, size_t ws_size,
                              hipStream_t stream) {
  const float* x     = (const float*)d_in[0];
  const float* Wqkv  = (const float*)d_in[1];
  const float* bqkv  = (const float*)d_in[2];
  const float* Wproj = (const float*)d_in[3];
  const float* bproj = (const float*)d_in[4];
  float* out = (float*)d_out;

  char* ws = (char*)d_ws;
  unsigned short* x_bf   = (unsigned short*)ws;                         // 32MB, reused as attn_out
  unsigned short* wqkvt  = (unsigned short*)(ws + 33554432);            // 24MB
  unsigned short* wprojt = (unsigned short*)(ws + 33554432 + 25165824); // 8MB
  unsigned short* qb     = (unsigned short*)(ws + 67108864);            // 32MB (pre-scaled)
  unsigned short* kb     = (unsigned short*)(ws + 100663296);           // 32MB
  unsigned short* vtb    = (unsigned short*)(ws + 134217728);           // 32MB [bh][d][t]

  (void)hipFuncSetAttribute((const void*)gemm_qkv256_kernel,
                            hipFuncAttributeMaxDynamicSharedMemorySize, 65536);
  (void)hipFuncSetAttribute((const void*)gemm_proj256_kernel,
                            hipFuncAttributeMaxDynamicSharedMemorySize, 131072);
  (void)hipFuncSetAttribute((const void*)attn_kernel,
                            hipFuncAttributeMaxDynamicSharedMemorySize, 65536);

  preproc_kernel<<<32768, 256, 0, stream>>>(x, Wqkv, Wproj, x_bf, wqkvt, wprojt);
  gemm_qkv256_kernel<<<1536, 256, 65536, stream>>>(x_bf, wqkvt, bqkv, qb, kb, vtb);
  attn_kernel<<<dim3(64, 4), 512, 65536, stream>>>(qb, kb, vtb, x_bf /* attn_out */);
  gemm_proj256_kernel<<<256, 512, 131072, stream>>>(x_bf, wprojt, bproj, out);
}